// Round 4
// baseline (397.767 us; speedup 1.0000x reference)
//
#include <hip/hip_runtime.h>

namespace {

constexpr int   kB     = 32768;
constexpr int   kT     = 50;
constexpr float kDT    = 0.01f;
constexpr float kGamma = 0.1f;
constexpr float kSigma = 0.2f;
constexpr float kTau   = 0.5f;

// Packed-weight workspace layout (float offsets).
constexpr int WS_L1  = 0;              // [4 waves][5 rows][20]  bias, w_t, w_x0..15, pad2
constexpr int WS_L2  = WS_L1  + 400;   // [4][5][12]             bias, w0..9, pad
constexpr int WS_L3  = WS_L2  + 240;   // [4][8][12]             bias, w0..9, pad (waves 2,3 use 4 rows)
constexpr int WS_UPD = WS_L3  + 384;   // [4][4][80]             Arow16 Brow8 Crow16 Drow8 Acol16 Ccol16
constexpr int WS_DH  = WS_UPD + 1280;  // [4][2][32]             Bcol16 Dcol16

__device__ __forceinline__ float ftanh(float x) {
  float e = exp2f(x * 2.8853900817779268f);   // exp(2x) via exp2
  return 1.0f - 2.0f * __builtin_amdgcn_rcpf(e + 1.0f);
}

// ---------------- prep: pack weights in per-wave consumption order ----------
__global__ __launch_bounds__(256) void prep_kernel(
    const float* __restrict__ A,   const float* __restrict__ Bm,
    const float* __restrict__ Cm,  const float* __restrict__ Dm,
    const float* __restrict__ pW1, const float* __restrict__ pb1,
    const float* __restrict__ pW2, const float* __restrict__ pb2,
    const float* __restrict__ pW3, const float* __restrict__ pb3,
    const float* __restrict__ zW1, const float* __restrict__ zb1,
    const float* __restrict__ zW2, const float* __restrict__ zb2,
    const float* __restrict__ zW3, const float* __restrict__ zb3,
    float* __restrict__ ws, float* __restrict__ out)
{
  const int tid = threadIdx.x;
  if (tid < 2) out[tid] = 0.0f;   // harness re-poisons out each replay
  // L1: waves 0,1 -> Z rows 0-4 / 5-9 ; waves 2,3 -> phi rows 0-4 / 5-9
  for (int c = tid; c < 20; c += 256) {
    int q = c / 5, r = c % 5;
    const float* W = (q < 2) ? zW1 : pW1;
    const float* b = (q < 2) ? zb1 : pb1;
    int row = 5 * (q & 1) + r;
    float* d = ws + WS_L1 + c * 20;
    d[0] = b[row];
    for (int k = 0; k < 17; ++k) d[1 + k] = W[k * 10 + row];
    d[18] = 0.f; d[19] = 0.f;
  }
  // L2
  for (int c = tid; c < 20; c += 256) {
    int q = c / 5, r = c % 5;
    const float* W = (q < 2) ? zW2 : pW2;
    const float* b = (q < 2) ? zb2 : pb2;
    int row = 5 * (q & 1) + r;
    float* d = ws + WS_L2 + c * 12;
    d[0] = b[row];
    for (int k = 0; k < 10; ++k) d[1 + k] = W[k * 10 + row];
    d[11] = 0.f;
  }
  // L3: waves 0,1 -> Zv rows (8 each, z-MLP); waves 2,3 -> u rows (4 each, phi)
  for (int c = tid; c < 32; c += 256) {
    int q = c / 8, r = c % 8;
    float* d = ws + WS_L3 + c * 12;
    if (q < 2) {
      int row = 8 * q + r;
      d[0] = zb3[row];
      for (int k = 0; k < 10; ++k) d[1 + k] = zW3[k * 16 + row];
      d[11] = 0.f;
    } else if (r < 4) {
      int row = 4 * (q - 2) + r;
      d[0] = pb3[row];
      for (int k = 0; k < 10; ++k) d[1 + k] = pW3[k * 8 + row];
      d[11] = 0.f;
    }
  }
  // UPD: per state row i: A row, B row, C row, D row, A col, C col
  for (int i = tid; i < 16; i += 256) {
    float* d = ws + WS_UPD + i * 80;
    for (int j = 0; j < 16; ++j) d[j]      = A [i * 16 + j];
    for (int j = 0; j < 8;  ++j) d[16 + j] = Bm[i * 8  + j];
    for (int j = 0; j < 16; ++j) d[24 + j] = Cm[i * 16 + j];
    for (int j = 0; j < 8;  ++j) d[40 + j] = Dm[i * 8  + j];
    for (int j = 0; j < 16; ++j) d[48 + j] = A [j * 16 + i];
    for (int j = 0; j < 16; ++j) d[64 + j] = Cm[j * 16 + i];
  }
  // DH: per control row i: B col, D col
  for (int i = tid; i < 8; i += 256) {
    float* d = ws + WS_DH + i * 32;
    for (int j = 0; j < 16; ++j) d[j]      = Bm[j * 8 + i];
    for (int j = 0; j < 16; ++j) d[16 + j] = Dm[j * 8 + i];
  }
}

// ---------------- main: 4 waves / 64 elements per block ---------------------
// (256,2): grid gives only 2 waves/SIMD, so let the allocator use up to 256
// VGPRs — R2's default budget (76 VGPR) caused remat/AGPR-spill VALU bloat.
__global__ __launch_bounds__(256, 2) void bsde_kernel(
    const float* __restrict__ dw,  const float* __restrict__ X0,
    const float* __restrict__ yW1, const float* __restrict__ yb1,
    const float* __restrict__ yW2, const float* __restrict__ yb2,
    const float* __restrict__ yW3, const float* __restrict__ yb3,
    const float* __restrict__ ws,  float* __restrict__ out)
{
  // Transposed [feature][lane] layouts: every LDS access is b32 with
  // lane-consecutive addresses -> structurally conflict-free (2 lanes/bank
  // aliasing is free on gfx950).
  __shared__ float XYt[32][64];   // X rows 0..15, Y rows 16..31
  __shared__ float H1Z[10][64], H1P[10][64];
  __shared__ float H2Z[10][64], H2P[10][64];
  __shared__ float ZUt[24][64];   // Zv rows 0..15, u rows 16..23

  const int lane = threadIdx.x & 63;
  const int q    = __builtin_amdgcn_readfirstlane((int)(threadIdx.x >> 6));
  const int e    = blockIdx.x * 64 + lane;

  const float* Wl1 = ws + WS_L1  + q * 100;
  const float* Wl2 = ws + WS_L2  + q * 60;
  const float* Wl3 = ws + WS_L3  + q * 96;
  const float* Wup = ws + WS_UPD + q * 320;
  const float* Wdh = ws + WS_DH  + q * 64;

  float (*H1)[64] = (q < 2) ? H1Z : H1P;
  float (*H2)[64] = (q < 2) ? H2Z : H2P;
  const int ro = (q & 1) * 5;

  // ---- X0 load + Y0 MLP (computed redundantly by every wave, one-time) ----
  float xf[16];
#pragma unroll
  for (int i = 0; i < 16; ++i) xf[i] = X0[e * 16 + i];

  float h1t[10], h2t[10], yf[16];
#pragma unroll
  for (int r = 0; r < 10; ++r) {
    float s = yb1[r];
#pragma unroll
    for (int k = 0; k < 16; ++k) s += xf[k] * yW1[k * 10 + r];
    h1t[r] = ftanh(s);
  }
#pragma unroll
  for (int r = 0; r < 10; ++r) {
    float s = yb2[r];
#pragma unroll
    for (int k = 0; k < 10; ++k) s += h1t[k] * yW2[k * 10 + r];
    h2t[r] = ftanh(s);
  }
#pragma unroll
  for (int r = 0; r < 16; ++r) {
    float s = yb3[r];
#pragma unroll
    for (int k = 0; k < 10; ++k) s += h2t[k] * yW3[k * 16 + r];
    yf[r] = s;
  }

  // Seed XYt before the loop (UPD phase reads own rows every t, incl. t=0).
  // yf is bit-identical across waves; one wave writes, first in-loop barrier
  // orders it before any read.
  if (q == 0) {
#pragma unroll
    for (int k = 0; k < 16; ++k) {
      XYt[k][lane]      = xf[k];
      XYt[16 + k][lane] = yf[k];
    }
  }

  float lcp = 0.0f;

  // ------------------------------- time loop -------------------------------
#pragma unroll 1
  for (int t = 0; t < kT; ++t) {
    const float tv  = (float)t * kDT;
    const float wt  = (t == 0 || t == kT - 1) ? 1.0f : 2.0f;
    const float dwv = dw[t * kB + e];

    // L1 (own MLP, 5 rows): packed row = [bias, w_t, w_x0..w_x15]
#pragma unroll
    for (int r = 0; r < 5; ++r) {
      const float* w = Wl1 + r * 20;
      float s = w[0] + tv * w[1];
#pragma unroll
      for (int k = 0; k < 16; ++k) s += xf[k] * w[2 + k];
      H1[ro + r][lane] = ftanh(s);
    }
    __syncthreads();
    float hh[10];
#pragma unroll
    for (int k = 0; k < 10; ++k) hh[k] = H1[k][lane];

    // L2 (own MLP, 5 rows)
#pragma unroll
    for (int r = 0; r < 5; ++r) {
      const float* w = Wl2 + r * 12;
      float s = w[0];
#pragma unroll
      for (int k = 0; k < 10; ++k) s += hh[k] * w[1 + k];
      H2[ro + r][lane] = ftanh(s);
    }
    __syncthreads();
#pragma unroll
    for (int k = 0; k < 10; ++k) hh[k] = H2[k][lane];

    // L3: waves 0,1 -> 8 Zv rows; waves 2,3 -> 4 u rows
    if (q < 2) {
#pragma unroll
      for (int r = 0; r < 8; ++r) {
        const float* w = Wl3 + r * 12;
        float s = w[0];
#pragma unroll
        for (int k = 0; k < 10; ++k) s += hh[k] * w[1 + k];
        ZUt[8 * q + r][lane] = s;
      }
    } else {
#pragma unroll
      for (int r = 0; r < 4; ++r) {
        const float* w = Wl3 + r * 12;
        float s = w[0];
#pragma unroll
        for (int k = 0; k < 10; ++k) s += hh[k] * w[1 + k];
        ZUt[16 + 4 * (q - 2) + r][lane] = s;
      }
    }
    __syncthreads();
    float zv[16], uf[8];
#pragma unroll
    for (int k = 0; k < 16; ++k) zv[k] = ZUt[k][lane];
#pragma unroll
    for (int k = 0; k < 8; ++k)  uf[k] = ZUt[16 + k][lane];

    // State updates: rows i = 4q..4q+3. Own-row scalars (runtime index i)
    // come from LDS -> no runtime-indexed register arrays, no scratch.
    float Xn[4], Yn[4];
#pragma unroll
    for (int r = 0; r < 4; ++r) {
      const int i = 4 * q + r;
      const float* w = Wup + r * 80;
      float dx = kGamma, fx = kSigma;
#pragma unroll
      for (int j = 0; j < 16; ++j) dx += w[j] * xf[j];
#pragma unroll
      for (int j = 0; j < 8;  ++j) dx += w[16 + j] * uf[j];
#pragma unroll
      for (int j = 0; j < 16; ++j) fx += w[24 + j] * xf[j];
#pragma unroll
      for (int j = 0; j < 8;  ++j) fx += w[40 + j] * uf[j];
      const float xi = XYt[i][lane];
      const float yi = XYt[16 + i][lane];
      const float zi = ZUt[i][lane];
      float dy = xi;
#pragma unroll
      for (int j = 0; j < 16; ++j) dy += w[48 + j] * yf[j] + w[64 + j] * zv[j];
      Xn[r] = xi + kDT * dx + dwv * fx;
      Yn[r] = yi - kDT * dy + dwv * zi;
    }

    // dH rows i = 2q, 2q+1
    float s2 = 0.0f;
#pragma unroll
    for (int r = 0; r < 2; ++r) {
      const int i = 2 * q + r;
      const float* w = Wdh + r * 32;
      float dh = ZUt[16 + i][lane];        // u[i]
#pragma unroll
      for (int j = 0; j < 16; ++j) dh += w[j] * yf[j] + w[16 + j] * zv[j];
      s2 += dh * dh;
    }
    lcp += (0.5f * kDT * kTau * kTau) * wt * s2;

    // Exchange updated state (own rows only; read-then-write wave-local, no
    // cross-wave hazard before the barrier)
#pragma unroll
    for (int r = 0; r < 4; ++r) XYt[4 * q + r][lane]      = Xn[r];
#pragma unroll
    for (int r = 0; r < 4; ++r) XYt[16 + 4 * q + r][lane] = Yn[r];
    __syncthreads();
#pragma unroll
    for (int k = 0; k < 16; ++k) xf[k] = XYt[k][lane];
#pragma unroll
    for (int k = 0; k < 16; ++k) yf[k] = XYt[16 + k][lane];
  }

  // ---- losses ----
  float bp = 0.0f;
  if (q == 0) {
#pragma unroll
    for (int i = 0; i < 16; ++i) { float d = yf[i] - xf[i]; bp += d * d; }
  }
#pragma unroll
  for (int s = 32; s > 0; s >>= 1) {
    bp  += __shfl_down(bp,  s, 64);
    lcp += __shfl_down(lcp, s, 64);
  }
  if (lane == 0) {
    if (q == 0) atomicAdd(&out[0], bp * (1.0f / (float)kB));
    atomicAdd(&out[1], lcp * (1.0f / (float)kB));
  }
}

} // namespace

extern "C" void kernel_launch(void* const* d_in, const int* in_sizes, int n_in,
                              void* d_out, int out_size, void* d_ws, size_t ws_size,
                              hipStream_t stream) {
  (void)in_sizes; (void)n_in; (void)ws_size; (void)out_size;

  const float* dw  = (const float*)d_in[0];
  const float* X0  = (const float*)d_in[1];
  const float* A   = (const float*)d_in[2];
  const float* Bm  = (const float*)d_in[3];
  const float* Cm  = (const float*)d_in[4];
  const float* Dm  = (const float*)d_in[5];
  const float* pW1 = (const float*)d_in[6];
  const float* pb1 = (const float*)d_in[7];
  const float* pW2 = (const float*)d_in[8];
  const float* pb2 = (const float*)d_in[9];
  const float* pW3 = (const float*)d_in[10];
  const float* pb3 = (const float*)d_in[11];
  const float* zW1 = (const float*)d_in[12];
  const float* zb1 = (const float*)d_in[13];
  const float* zW2 = (const float*)d_in[14];
  const float* zb2 = (const float*)d_in[15];
  const float* zW3 = (const float*)d_in[16];
  const float* zb3 = (const float*)d_in[17];
  const float* yW1 = (const float*)d_in[18];
  const float* yb1 = (const float*)d_in[19];
  const float* yW2 = (const float*)d_in[20];
  const float* yb2 = (const float*)d_in[21];
  const float* yW3 = (const float*)d_in[22];
  const float* yb3 = (const float*)d_in[23];
  float* out = (float*)d_out;
  float* ws  = (float*)d_ws;

  prep_kernel<<<1, 256, 0, stream>>>(
      A, Bm, Cm, Dm,
      pW1, pb1, pW2, pb2, pW3, pb3,
      zW1, zb1, zW2, zb2, zW3, zb3, ws, out);

  bsde_kernel<<<kB / 64, 256, 0, stream>>>(
      dw, X0, yW1, yb1, yW2, yb2, yW3, yb3, ws, out);
}

// Round 5
// 332.128 us; speedup vs baseline: 1.1976x; 1.1976x over previous
//
#include <hip/hip_runtime.h>

namespace {

typedef float v4f __attribute__((ext_vector_type(4)));

constexpr int   kB     = 32768;
constexpr int   kT     = 50;
constexpr float kDT    = 0.01f;
constexpr float kGamma = 0.1f;
constexpr float kSigma = 0.2f;
constexpr float kTau   = 0.5f;

// Packed-weight workspace layout (float offsets).
constexpr int WS_L1  = 0;              // [4 waves][5 rows][20]  bias, w_t, w_x0..15, pad2
constexpr int WS_L2  = WS_L1  + 400;   // [4][5][12]             bias, w0..9, pad
constexpr int WS_L3  = WS_L2  + 240;   // [4][8][12]             bias, w0..9, pad (waves 2,3 use 4 rows)
constexpr int WS_UPD = WS_L3  + 384;   // [4][4][80]             Arow16 Brow8 Crow16 Drow8 Acol16 Ccol16
constexpr int WS_DH  = WS_UPD + 1280;  // [4][2][32]             Bcol16 Dcol16

__device__ __forceinline__ float ftanh(float x) {
  float e = exp2f(x * 2.8853900817779268f);   // exp(2x) via exp2
  return 1.0f - 2.0f * __builtin_amdgcn_rcpf(e + 1.0f);
}

// ---------------- prep: pack weights in per-wave consumption order ----------
__global__ __launch_bounds__(256) void prep_kernel(
    const float* __restrict__ A,   const float* __restrict__ Bm,
    const float* __restrict__ Cm,  const float* __restrict__ Dm,
    const float* __restrict__ pW1, const float* __restrict__ pb1,
    const float* __restrict__ pW2, const float* __restrict__ pb2,
    const float* __restrict__ pW3, const float* __restrict__ pb3,
    const float* __restrict__ zW1, const float* __restrict__ zb1,
    const float* __restrict__ zW2, const float* __restrict__ zb2,
    const float* __restrict__ zW3, const float* __restrict__ zb3,
    float* __restrict__ ws, float* __restrict__ out)
{
  const int tid = threadIdx.x;
  if (tid < 2) out[tid] = 0.0f;   // harness re-poisons out each replay
  for (int c = tid; c < 20; c += 256) {
    int q = c / 5, r = c % 5;
    const float* W = (q < 2) ? zW1 : pW1;
    const float* b = (q < 2) ? zb1 : pb1;
    int row = 5 * (q & 1) + r;
    float* d = ws + WS_L1 + c * 20;
    d[0] = b[row];
    for (int k = 0; k < 17; ++k) d[1 + k] = W[k * 10 + row];
    d[18] = 0.f; d[19] = 0.f;
  }
  for (int c = tid; c < 20; c += 256) {
    int q = c / 5, r = c % 5;
    const float* W = (q < 2) ? zW2 : pW2;
    const float* b = (q < 2) ? zb2 : pb2;
    int row = 5 * (q & 1) + r;
    float* d = ws + WS_L2 + c * 12;
    d[0] = b[row];
    for (int k = 0; k < 10; ++k) d[1 + k] = W[k * 10 + row];
    d[11] = 0.f;
  }
  for (int c = tid; c < 32; c += 256) {
    int q = c / 8, r = c % 8;
    float* d = ws + WS_L3 + c * 12;
    if (q < 2) {
      int row = 8 * q + r;
      d[0] = zb3[row];
      for (int k = 0; k < 10; ++k) d[1 + k] = zW3[k * 16 + row];
      d[11] = 0.f;
    } else if (r < 4) {
      int row = 4 * (q - 2) + r;
      d[0] = pb3[row];
      for (int k = 0; k < 10; ++k) d[1 + k] = pW3[k * 8 + row];
      d[11] = 0.f;
    }
  }
  for (int i = tid; i < 16; i += 256) {
    float* d = ws + WS_UPD + i * 80;
    for (int j = 0; j < 16; ++j) d[j]      = A [i * 16 + j];
    for (int j = 0; j < 8;  ++j) d[16 + j] = Bm[i * 8  + j];
    for (int j = 0; j < 16; ++j) d[24 + j] = Cm[i * 16 + j];
    for (int j = 0; j < 8;  ++j) d[40 + j] = Dm[i * 8  + j];
    for (int j = 0; j < 16; ++j) d[48 + j] = A [j * 16 + i];
    for (int j = 0; j < 16; ++j) d[64 + j] = Cm[j * 16 + i];
  }
  for (int i = tid; i < 8; i += 256) {
    float* d = ws + WS_DH + i * 32;
    for (int j = 0; j < 16; ++j) d[j]      = Bm[j * 8 + i];
    for (int j = 0; j < 16; ++j) d[16 + j] = Dm[j * 8 + i];
  }
}

// Wave-specialized state update + dH (Q is compile-time -> all own-row values
// are constant-index register accesses, zero LDS).
template <int Q>
__device__ __forceinline__ void upd_body(
    const float* __restrict__ Wup, const float* __restrict__ Wdh,
    const v4f xf4[4], const v4f yf4[4], const v4f zvf[4], const v4f uff[2],
    float dwv, float* __restrict__ Xn, float* __restrict__ Yn, float& s2)
{
#pragma unroll
  for (int r = 0; r < 4; ++r) {
    const float* w = Wup + r * 80;
    float dx = kGamma, fx = kSigma;
#pragma unroll
    for (int c = 0; c < 4; ++c)
#pragma unroll
      for (int j = 0; j < 4; ++j) {
        dx += w[4 * c + j]      * xf4[c][j];
        fx += w[24 + 4 * c + j] * xf4[c][j];
      }
#pragma unroll
    for (int c = 0; c < 2; ++c)
#pragma unroll
      for (int j = 0; j < 4; ++j) {
        dx += w[16 + 4 * c + j] * uff[c][j];
        fx += w[40 + 4 * c + j] * uff[c][j];
      }
    const float xi = xf4[Q][r];
    const float yi = yf4[Q][r];
    const float zi = zvf[Q][r];
    float dy = xi;
#pragma unroll
    for (int c = 0; c < 4; ++c)
#pragma unroll
      for (int j = 0; j < 4; ++j)
        dy += w[48 + 4 * c + j] * yf4[c][j] + w[64 + 4 * c + j] * zvf[c][j];
    Xn[r] = xi + kDT * dx + dwv * fx;
    Yn[r] = yi - kDT * dy + dwv * zi;
  }
#pragma unroll
  for (int r = 0; r < 2; ++r) {
    const float* w = Wdh + r * 32;
    float dh = uff[(2 * Q + r) >> 2][(2 * Q + r) & 3];
#pragma unroll
    for (int c = 0; c < 4; ++c)
#pragma unroll
      for (int j = 0; j < 4; ++j)
        dh += w[4 * c + j] * yf4[c][j] + w[16 + 4 * c + j] * zvf[c][j];
    s2 += dh * dh;
  }
}

// ---------------- main: 4 waves / 64 elements per block ---------------------
__global__ __launch_bounds__(256, 2) void bsde_kernel(
    const float* __restrict__ dw,  const float* __restrict__ X0,
    const float* __restrict__ yW1, const float* __restrict__ yb1,
    const float* __restrict__ yW2, const float* __restrict__ yb2,
    const float* __restrict__ yW3, const float* __restrict__ yb3,
    const float* __restrict__ ws,  float* __restrict__ out)
{
  // Non-multiple-of-32 dword strides (36,12,28), 16B-aligned rows -> b128
  // accesses rotate across all banks (bandwidth floor, no conflicts).
  __shared__ float XYt[64][36];   // dwords 0..15 = X (chunks 0-3), 16..31 = Y (4-7)
  __shared__ float H1Z[64][12], H1P[64][12];
  __shared__ float H2Z[64][12], H2P[64][12];
  __shared__ float ZUt[64][28];   // 0..15 = Zv (chunks 0-3), 16..23 = u (4-5)

  const int lane = threadIdx.x & 63;
  const int q    = __builtin_amdgcn_readfirstlane((int)(threadIdx.x >> 6));
  const int e    = blockIdx.x * 64 + lane;

  const float* Wl1 = ws + WS_L1  + q * 100;
  const float* Wl2 = ws + WS_L2  + q * 60;
  const float* Wl3 = ws + WS_L3  + q * 96;
  const float* Wup = ws + WS_UPD + q * 320;
  const float* Wdh = ws + WS_DH  + q * 64;

  float (*H1)[12] = (q < 2) ? H1Z : H1P;
  float (*H2)[12] = (q < 2) ? H2Z : H2P;
  const int ro = (q & 1) * 5;

  // ---- X0 load (b128) + Y0 MLP (redundant per wave, one-time) ----
  v4f x0[4];
#pragma unroll
  for (int c = 0; c < 4; ++c) x0[c] = *(const v4f*)&X0[e * 16 + 4 * c];

  float h1t[10], h2t[10], yf0[16];
#pragma unroll
  for (int r = 0; r < 10; ++r) {
    float s = yb1[r];
#pragma unroll
    for (int c = 0; c < 4; ++c)
#pragma unroll
      for (int j = 0; j < 4; ++j) s += x0[c][j] * yW1[(4 * c + j) * 10 + r];
    h1t[r] = ftanh(s);
  }
#pragma unroll
  for (int r = 0; r < 10; ++r) {
    float s = yb2[r];
#pragma unroll
    for (int k = 0; k < 10; ++k) s += h1t[k] * yW2[k * 10 + r];
    h2t[r] = ftanh(s);
  }
#pragma unroll
  for (int r = 0; r < 16; ++r) {
    float s = yb3[r];
#pragma unroll
    for (int k = 0; k < 10; ++k) s += h2t[k] * yW3[k * 16 + r];
    yf0[r] = s;
  }

  // Seed XYt (wave 0 only; values bit-identical across waves), then barrier.
  if (q == 0) {
#pragma unroll
    for (int c = 0; c < 4; ++c) {
      *(v4f*)&XYt[lane][4 * c]      = x0[c];
      v4f yv = {yf0[4 * c], yf0[4 * c + 1], yf0[4 * c + 2], yf0[4 * c + 3]};
      *(v4f*)&XYt[lane][16 + 4 * c] = yv;
    }
  }
  __syncthreads();

  float lcp = 0.0f;
  float Xn[4], Yn[4];
  float dwv = dw[e];   // t=0 increment

  // ------------------------------- time loop -------------------------------
#pragma unroll 1
  for (int t = 0; t < kT; ++t) {
    // Prefetch next step's dw (used only at UPD -> ~3 barrier phases of slack)
    float dwn = 0.0f;
    if (t < kT - 1) dwn = dw[(t + 1) * kB + e];

    const float tv = (float)t * kDT;
    const float wt = (t == 0 || t == kT - 1) ? 1.0f : 2.0f;

    // Top: read full state (b128), pin in registers.
    v4f xf4[4], yf4[4];
#pragma unroll
    for (int c = 0; c < 4; ++c) {
      xf4[c] = *(const v4f*)&XYt[lane][4 * c];
      yf4[c] = *(const v4f*)&XYt[lane][16 + 4 * c];
    }
    asm volatile("" : "+v"(xf4[0]), "+v"(xf4[1]), "+v"(xf4[2]), "+v"(xf4[3]),
                      "+v"(yf4[0]), "+v"(yf4[1]), "+v"(yf4[2]), "+v"(yf4[3]));

    // L1 (own MLP, 5 rows): packed row = [bias, w_t, w_x0..w_x15]
#pragma unroll
    for (int r = 0; r < 5; ++r) {
      const float* w = Wl1 + r * 20;
      float s = w[0] + tv * w[1];
#pragma unroll
      for (int c = 0; c < 4; ++c)
#pragma unroll
        for (int j = 0; j < 4; ++j) s += xf4[c][j] * w[2 + 4 * c + j];
      H1[lane][ro + r] = ftanh(s);
    }
    __syncthreads();
    v4f hh[3];
#pragma unroll
    for (int c = 0; c < 3; ++c) hh[c] = *(const v4f*)&H1[lane][4 * c];
    asm volatile("" : "+v"(hh[0]), "+v"(hh[1]), "+v"(hh[2]));

    // L2 (own MLP, 5 rows) — only dwords 0..9 of hh are data
#pragma unroll
    for (int r = 0; r < 5; ++r) {
      const float* w = Wl2 + r * 12;
      float s = w[0];
#pragma unroll
      for (int k = 0; k < 10; ++k) s += hh[k >> 2][k & 3] * w[1 + k];
      H2[lane][ro + r] = ftanh(s);
    }
    __syncthreads();
#pragma unroll
    for (int c = 0; c < 3; ++c) hh[c] = *(const v4f*)&H2[lane][4 * c];
    asm volatile("" : "+v"(hh[0]), "+v"(hh[1]), "+v"(hh[2]));

    // L3: waves 0,1 -> 8 Zv rows (2 b128 stores); waves 2,3 -> 4 u rows (1)
    if (q < 2) {
      float z[8];
#pragma unroll
      for (int r = 0; r < 8; ++r) {
        const float* w = Wl3 + r * 12;
        float s = w[0];
#pragma unroll
        for (int k = 0; k < 10; ++k) s += hh[k >> 2][k & 3] * w[1 + k];
        z[r] = s;
      }
      v4f z0 = {z[0], z[1], z[2], z[3]}, z1 = {z[4], z[5], z[6], z[7]};
      *(v4f*)&ZUt[lane][8 * q]     = z0;
      *(v4f*)&ZUt[lane][8 * q + 4] = z1;
    } else {
      float z[4];
#pragma unroll
      for (int r = 0; r < 4; ++r) {
        const float* w = Wl3 + r * 12;
        float s = w[0];
#pragma unroll
        for (int k = 0; k < 10; ++k) s += hh[k >> 2][k & 3] * w[1 + k];
        z[r] = s;
      }
      v4f zz = {z[0], z[1], z[2], z[3]};
      *(v4f*)&ZUt[lane][16 + 4 * (q - 2)] = zz;
    }
    __syncthreads();

    v4f zvf[4], uff[2];
#pragma unroll
    for (int c = 0; c < 4; ++c) zvf[c] = *(const v4f*)&ZUt[lane][4 * c];
#pragma unroll
    for (int c = 0; c < 2; ++c) uff[c] = *(const v4f*)&ZUt[lane][16 + 4 * c];
    asm volatile("" : "+v"(zvf[0]), "+v"(zvf[1]), "+v"(zvf[2]), "+v"(zvf[3]),
                      "+v"(uff[0]), "+v"(uff[1]));

    // UPD + dH, wave-specialized (uniform branch, no divergence)
    float s2 = 0.0f;
    if      (q == 0) upd_body<0>(Wup, Wdh, xf4, yf4, zvf, uff, dwv, Xn, Yn, s2);
    else if (q == 1) upd_body<1>(Wup, Wdh, xf4, yf4, zvf, uff, dwv, Xn, Yn, s2);
    else if (q == 2) upd_body<2>(Wup, Wdh, xf4, yf4, zvf, uff, dwv, Xn, Yn, s2);
    else             upd_body<3>(Wup, Wdh, xf4, yf4, zvf, uff, dwv, Xn, Yn, s2);
    lcp += (0.5f * kDT * kTau * kTau) * wt * s2;

    // Publish own rows (b128), end-of-iteration barrier.
    {
      v4f xs = {Xn[0], Xn[1], Xn[2], Xn[3]};
      v4f ys = {Yn[0], Yn[1], Yn[2], Yn[3]};
      *(v4f*)&XYt[lane][4 * q]      = xs;
      *(v4f*)&XYt[lane][16 + 4 * q] = ys;
    }
    dwv = dwn;
    __syncthreads();
  }

  // ---- losses: every wave holds its own 4 final rows in Xn/Yn ----
  float bp = 0.0f;
#pragma unroll
  for (int r = 0; r < 4; ++r) { float d = Yn[r] - Xn[r]; bp += d * d; }

#pragma unroll
  for (int s = 32; s > 0; s >>= 1) {
    bp  += __shfl_down(bp,  s, 64);
    lcp += __shfl_down(lcp, s, 64);
  }
  if (lane == 0) {
    atomicAdd(&out[0], bp  * (1.0f / (float)kB));
    atomicAdd(&out[1], lcp * (1.0f / (float)kB));
  }
}

} // namespace

extern "C" void kernel_launch(void* const* d_in, const int* in_sizes, int n_in,
                              void* d_out, int out_size, void* d_ws, size_t ws_size,
                              hipStream_t stream) {
  (void)in_sizes; (void)n_in; (void)ws_size; (void)out_size;

  const float* dw  = (const float*)d_in[0];
  const float* X0  = (const float*)d_in[1];
  const float* A   = (const float*)d_in[2];
  const float* Bm  = (const float*)d_in[3];
  const float* Cm  = (const float*)d_in[4];
  const float* Dm  = (const float*)d_in[5];
  const float* pW1 = (const float*)d_in[6];
  const float* pb1 = (const float*)d_in[7];
  const float* pW2 = (const float*)d_in[8];
  const float* pb2 = (const float*)d_in[9];
  const float* pW3 = (const float*)d_in[10];
  const float* pb3 = (const float*)d_in[11];
  const float* zW1 = (const float*)d_in[12];
  const float* zb1 = (const float*)d_in[13];
  const float* zW2 = (const float*)d_in[14];
  const float* zb2 = (const float*)d_in[15];
  const float* zW3 = (const float*)d_in[16];
  const float* zb3 = (const float*)d_in[17];
  const float* yW1 = (const float*)d_in[18];
  const float* yb1 = (const float*)d_in[19];
  const float* yW2 = (const float*)d_in[20];
  const float* yb2 = (const float*)d_in[21];
  const float* yW3 = (const float*)d_in[22];
  const float* yb3 = (const float*)d_in[23];
  float* out = (float*)d_out;
  float* ws  = (float*)d_ws;

  prep_kernel<<<1, 256, 0, stream>>>(
      A, Bm, Cm, Dm,
      pW1, pb1, pW2, pb2, pW3, pb3,
      zW1, zb1, zW2, zb2, zW3, zb3, ws, out);

  bsde_kernel<<<kB / 64, 256, 0, stream>>>(
      dw, X0, yW1, yb1, yW2, yb2, yW3, yb3, ws, out);
}